// Round 5
// baseline (1277.482 us; speedup 1.0000x reference)
//
#include <hip/hip_runtime.h>
#include <hip/hip_bf16.h>
#include <stdint.h>

// Problem constants
#define NN 50000            // nodes
#define RR 33               // relations
#define EE 3200000          // edges
#define DD 1600             // emb dim
#define WSZ 16              // weights_size
#define CC 10               // classes
#define NC (RR*WSZ)         // 528 columns of H / H2
#define NCP 640             // padded to 5 * 128 column tiles

// Bucketed-scatter params
#define NBK 64              // bucket slots (49 used)
#define BSH 10              // bucket = s >> 10  (1024 nodes/bucket)
#define NBUSED ((NN + (1<<BSH) - 1) >> BSH)   // 49
#define MEDG 4096           // edges staged per block in pass A

typedef __attribute__((ext_vector_type(8))) short bfrag;   // 8 bf16 = 4 VGPRs
typedef __attribute__((ext_vector_type(4))) float f32x4;

__device__ __forceinline__ unsigned short f2bf(float f) {
  union { float f; unsigned u; } v; v.f = f;
  unsigned r = v.u + 0x7FFF + ((v.u >> 16) & 1);   // RNE, inputs are finite
  return (unsigned short)(r >> 16);
}
__device__ __forceinline__ float bf2f(unsigned short h) {
  union { unsigned u; float f; } v; v.u = ((unsigned)h) << 16;
  return v.f;
}
// pack two fp32 -> two bf16 (round-to-nearest via +0x8000 bias; ~1 ulp max)
__device__ __forceinline__ unsigned pack2bf(float a, float b) {
  unsigned ua = __float_as_uint(a) + 0x8000u;
  unsigned ub = __float_as_uint(b) + 0x8000u;
  return (ua >> 16) | (ub & 0xFFFF0000u);
}

// ---------------- 1) fused: build B^T bf16 + edge_s histogram -----------------
// blocks [0, 4000): Bt[n][k] = w1[n>>4][k][n&15]; blocks [4000, 16500): hist
__global__ __launch_bounds__(256) void k_bt_hist(const float* __restrict__ w1,
                                                 __hip_bfloat16* __restrict__ bt,
                                                 const int* __restrict__ es,
                                                 int* __restrict__ counts) {
  int b = blockIdx.x;
  if (b < 4000) {
    int idx = b * 256 + threadIdx.x;                   // NCP*DD = 1,024,000 exact
    int n = idx / DD, k = idx - n * DD;
    float v = 0.f;
    if (n < NC) {
      int r = n >> 4, o = n & 15;
      v = w1[((size_t)r * DD + k) * WSZ + o];
    }
    *reinterpret_cast<unsigned short*>(&bt[idx]) = f2bf(v);
  } else {
    int i = (b - 4000) * 256 + threadIdx.x;            // EE exact
    atomicAdd(&counts[es[i]], 1);
  }
}

// ---------------- 3b-i) per-1024-chunk partial sums (coalesced) ---------------
__global__ __launch_bounds__(256) void k_part(const int* __restrict__ counts,
                                              int* __restrict__ part) {
  int b = blockIdx.x, t = threadIdx.x;                 // NBUSED blocks
  int base = b << BSH;
  int s = 0;
  for (int j = t; j < (1 << BSH); j += 256) {
    int i = base + j; if (i < NN) s += counts[i];
  }
#pragma unroll
  for (int off = 32; off; off >>= 1) s += __shfl_down(s, off, 64);
  __shared__ int ws[4];
  if ((t & 63) == 0) ws[t >> 6] = s;
  __syncthreads();
  if (t == 0) part[b] = ws[0] + ws[1] + ws[2] + ws[3];
}

// ---------------- 3b-ii) scan 49 partials (one wave) --------------------------
__global__ __launch_bounds__(64) void k_scan2(const int* __restrict__ part,
                                              int* __restrict__ bbase,
                                              int* __restrict__ bptr,
                                              int* __restrict__ offs) {
  int t = threadIdx.x;
  int v = (t < NBUSED) ? part[t] : 0;
  int incl = v;
#pragma unroll
  for (int off = 1; off < 64; off <<= 1) {
    int x = __shfl_up(incl, off, 64);
    if (t >= off) incl += x;
  }
  int excl = incl - v;
  if (t < NBUSED) { bbase[t] = excl; bptr[t] = excl; }
  else if (t < NBK) bptr[t] = EE;
  if (t == 63) offs[NN] = EE;                          // all edges counted
}

// ---------------- 3b-iii) per-chunk exclusive scan -> offs/ptr ----------------
__global__ __launch_bounds__(1024) void k_offs(const int* __restrict__ counts,
                                               const int* __restrict__ bbase,
                                               int* __restrict__ offs,
                                               int* __restrict__ ptr) {
  __shared__ int sc[1024];
  int b = blockIdx.x, t = threadIdx.x;                 // NBUSED blocks x 1024
  int node = (b << BSH) + t;
  int v = (node < NN) ? counts[node] : 0;
  sc[t] = v;
  __syncthreads();
  for (int off = 1; off < 1024; off <<= 1) {
    int x = (t >= off) ? sc[t - off] : 0;
    __syncthreads();
    sc[t] += x;
    __syncthreads();
  }
  int excl = sc[t] - v + bbase[b];
  if (node < NN) { offs[node] = excl; ptr[node] = excl; }
}

// ---------------- 3c pass A) LDS-staged bucket binning ------------------------
// tmp records grouped by bucket (s>>10); r.x = o | p<<16 | (s&1023)<<22
__global__ __launch_bounds__(256) void k_bucket(const int* __restrict__ es,
                                                const int* __restrict__ ep,
                                                const int* __restrict__ eo,
                                                const float* __restrict__ ev,
                                                int* __restrict__ bptr,
                                                uint2* __restrict__ tmp) {
  __shared__ int lhist[NBK];
  __shared__ int lofs[NBK];
  __shared__ int lcur[NBK];
  __shared__ int lbase[NBK];
  __shared__ uint2 stage[MEDG];
  __shared__ unsigned char sbk[MEDG];
  int tid = threadIdx.x;
  int e0 = blockIdx.x * MEDG;
  int n = EE - e0; if (n > MEDG) n = MEDG;
  for (int i = tid; i < NBK; i += 256) lhist[i] = 0;
  __syncthreads();
  for (int i = tid; i < n; i += 256)
    atomicAdd(&lhist[es[e0 + i] >> BSH], 1);
  __syncthreads();
  if (tid == 0) {
    int run = 0;
    for (int b = 0; b < NBK; ++b) { lofs[b] = run; run += lhist[b]; }
  }
  __syncthreads();
  if (tid < NBK) {
    lcur[tid] = lofs[tid];
    lbase[tid] = lhist[tid] ? atomicAdd(&bptr[tid], lhist[tid]) : 0;
  }
  __syncthreads();
  for (int i = tid; i < n; i += 256) {
    int s = es[e0 + i];
    int b = s >> BSH;
    int pos = atomicAdd(&lcur[b], 1);
    uint2 r;
    r.x = (unsigned)eo[e0 + i] | ((unsigned)ep[e0 + i] << 16)
        | ((unsigned)(s & 1023) << 22);
    r.y = __float_as_uint(ev[e0 + i]);
    stage[pos] = r;
    sbk[pos] = (unsigned char)b;
  }
  __syncthreads();
  for (int i = tid; i < n; i += 256) {                 // grouped -> ~sequential writes
    int b = sbk[i];
    tmp[lbase[b] + (i - lofs[b])] = stage[i];
  }
}

// ---------------- 3c pass B) within-bucket CSR scatter (L2-resident) ----------
#define SBPB 8               // sub-blocks per bucket
__global__ __launch_bounds__(256) void k_scatter2(const uint2* __restrict__ tmp,
                                                  const int* __restrict__ offs,
                                                  int* __restrict__ ptr,
                                                  uint2* __restrict__ recs) {
  int b = blockIdx.x;                                  // NBUSED x SBPB grid
  int n0 = b << BSH, n1 = (b + 1) << BSH;
  if (n1 > NN) n1 = NN;
  int start = offs[n0], endv = offs[n1];
  int tid = blockIdx.y * 256 + (int)threadIdx.x;
  for (int i = start + tid; i < endv; i += SBPB * 256) {
    uint2 r = tmp[i];
    int s = n0 + (int)(r.x >> 22);
    int pos = atomicAdd(&ptr[s], 1);
    recs[pos] = r;                                     // random within ~512KB: L2 absorbs
  }
}

// ---------------- 4) GEMM: Hb = emb(fp32, converted in-staging) @ B, bf16 out -
#define BM 128
#define BN 128
#define BK 32

__global__ __launch_bounds__(256) void k_gemm(const float* __restrict__ A,
                                              const __hip_bfloat16* __restrict__ Bt,
                                              __hip_bfloat16* __restrict__ Hb) {
  __shared__ __align__(16) __hip_bfloat16 As[BM * BK];   // [row][k]
  __shared__ __align__(16) __hip_bfloat16 Bs[BN * BK];   // [col][k] (Bt layout)
  int tid  = threadIdx.x;
  int wave = tid >> 6, lane = tid & 63;
  int n0 = blockIdx.x * BN;                              // n-tile FAST: A strip shared
  int m0 = blockIdx.y * BM;                              // by 5 adjacent blocks (L3)
  int wm = (wave >> 1) * 64, wn = (wave & 1) * 64;       // 2x2 wave quadrants
  int ld = lane & 15, quad = lane >> 4;

  // active-column mask per ni (wave-uniform): skip padded cols >= NC
  bool nact[4];
#pragma unroll
  for (int ni = 0; ni < 4; ++ni) nact[ni] = (n0 + wn + ni * 16) < NC;

  // A-staging addresses: 2 chunks of (row = idx>>2, kc = (idx&3)*8)
  int rowA[2], kcA[2];
#pragma unroll
  for (int j = 0; j < 2; ++j) {
    int idx = j * 256 + tid;
    int row = idx >> 2;
    kcA[j] = (idx & 3) * 8;
    int grow = m0 + row; if (grow > NN - 1) grow = NN - 1;
    rowA[j] = grow;
  }

  f32x4 acc[4][4] = {};

  for (int k0 = 0; k0 < DD; k0 += BK) {
    __syncthreads();
    // stage A: fp32 global -> round/pack -> bf16 LDS (8 elems / thread / chunk)
#pragma unroll
    for (int j = 0; j < 2; ++j) {
      const float4* gp = (const float4*)(A + (size_t)rowA[j] * DD + k0 + kcA[j]);
      float4 v0 = gp[0], v1 = gp[1];
      uint4 w;
      w.x = pack2bf(v0.x, v0.y); w.y = pack2bf(v0.z, v0.w);
      w.z = pack2bf(v1.x, v1.y); w.w = pack2bf(v1.z, v1.w);
      *reinterpret_cast<uint4*>(As + ((size_t)j * 256 + tid) * 8) = w;
    }
    // stage B: async DMA, bf16 already
#pragma unroll
    for (int j = 0; j < 2; ++j) {
      int idx = j * 256 + tid;
      int col = idx >> 2;
      int kc  = (idx & 3) * 8;
      const __hip_bfloat16* gp = Bt + (size_t)(n0 + col) * DD + k0 + kc;
      __builtin_amdgcn_global_load_lds(
          (const __attribute__((address_space(1))) void*)gp,
          (__attribute__((address_space(3))) void*)(Bs + idx * 8), 16, 0, 0);
    }
    __syncthreads();                                     // drains vmcnt + lgkmcnt

    bfrag af[4], bf[4];
#pragma unroll
    for (int mi = 0; mi < 4; ++mi)
      af[mi] = *(const bfrag*)(As + (wm + mi * 16 + ld) * BK + quad * 8);
#pragma unroll
    for (int ni = 0; ni < 4; ++ni)
      if (nact[ni])
        bf[ni] = *(const bfrag*)(Bs + (wn + ni * 16 + ld) * BK + quad * 8);
#pragma unroll
    for (int mi = 0; mi < 4; ++mi)
#pragma unroll
      for (int ni = 0; ni < 4; ++ni)
        if (nact[ni])
          acc[mi][ni] = __builtin_amdgcn_mfma_f32_16x16x32_bf16(af[mi], bf[ni],
                                                                acc[mi][ni], 0, 0, 0);
  }

#pragma unroll
  for (int mi = 0; mi < 4; ++mi)
#pragma unroll
    for (int ni = 0; ni < 4; ++ni) {
      int col = n0 + wn + ni * 16 + ld;
      if (col >= NC) continue;
#pragma unroll
      for (int r = 0; r < 4; ++r) {
        int row = m0 + wm + mi * 16 + quad * 4 + r;      // C/D: col=lane&15, row=quad*4+reg
        if (row < NN)
          *reinterpret_cast<unsigned short*>(&Hb[(size_t)row * NC + col]) =
              f2bf(acc[mi][ni][r]);
      }
    }
}

// ---------------- 5) layer-1 aggregation: one wave per destination node -------
__global__ __launch_bounds__(256) void k_agg1(const uint2* __restrict__ recs,
                                              const int* __restrict__ offs,
                                              const __hip_bfloat16* __restrict__ Hb,
                                              const float* __restrict__ bias1,
                                              float* __restrict__ h1) {
  int wid  = (blockIdx.x * 256 + threadIdx.x) >> 6;      // exactly NN waves
  int lane = threadIdx.x & 63;
  int grp = lane >> 4, c = lane & 15;
  int beg = offs[wid], end = offs[wid + 1];
  float acc = 0.f;
  int e = beg + grp;
  for (; e + 4 < end; e += 8) {                          // 2x unroll: 2 chains in flight
    uint2 r0 = recs[e];
    uint2 r1 = recs[e + 4];
    int o0 = r0.x & 0xFFFF, p0 = (r0.x >> 16) & 0x3F;
    int o1 = r1.x & 0xFFFF, p1 = (r1.x >> 16) & 0x3F;
    unsigned short h0 = *reinterpret_cast<const unsigned short*>(
        &Hb[(size_t)o0 * NC + p0 * WSZ + c]);
    unsigned short h1v = *reinterpret_cast<const unsigned short*>(
        &Hb[(size_t)o1 * NC + p1 * WSZ + c]);
    acc += __uint_as_float(r0.y) * bf2f(h0);
    acc += __uint_as_float(r1.y) * bf2f(h1v);
  }
  if (e < end) {
    uint2 r = recs[e];
    int o = r.x & 0xFFFF, p = (r.x >> 16) & 0x3F;
    unsigned short h = *reinterpret_cast<const unsigned short*>(
        &Hb[(size_t)o * NC + p * WSZ + c]);
    acc += __uint_as_float(r.y) * bf2f(h);
  }
  acc += __shfl_xor(acc, 16, 64);
  acc += __shfl_xor(acc, 32, 64);
  if (lane < 16) h1[wid * WSZ + c] = fmaxf(acc + bias1[c], 0.f);
}

// ---------------- 6a) dense layer-2 projection: H2[n][p*16+c], bf16 out -------
__global__ __launch_bounds__(256) void k_h2(const float* __restrict__ h1,
                                            const float* __restrict__ w2,
                                            __hip_bfloat16* __restrict__ H2) {
  __shared__ float w2s[RR * WSZ * CC];                   // 21.1 KB
  for (int i = threadIdx.x; i < RR * WSZ * CC; i += 256) w2s[i] = w2[i];
  __syncthreads();
  int idx = blockIdx.x * 256 + threadIdx.x;              // NN*NC = 26,400,000 exact
  int n = idx / NC, j = idx - n * NC;
  int p = j >> 4, c = j & 15;
  float dot = 0.f;
  if (c < CC) {
    const float* hp = h1 + n * WSZ;
    const float* wp = w2s + p * WSZ * CC + c;
#pragma unroll
    for (int i2 = 0; i2 < WSZ; ++i2) dot += hp[i2] * wp[i2 * CC];
  }
  *reinterpret_cast<unsigned short*>(&H2[idx]) = f2bf(dot);
}

// ---------------- 6b) layer-2 aggregation: pure gather ------------------------
__global__ __launch_bounds__(256) void k_agg2(const uint2* __restrict__ recs,
                                              const int* __restrict__ offs,
                                              const __hip_bfloat16* __restrict__ H2,
                                              const float* __restrict__ bias2,
                                              float* __restrict__ out) {
  int wid  = (blockIdx.x * 256 + threadIdx.x) >> 6;      // exactly NN waves
  int lane = threadIdx.x & 63;
  int grp = lane >> 4, c = lane & 15;
  int beg = offs[wid], end = offs[wid + 1];
  float acc = 0.f;
  int e = beg + grp;
  for (; e + 4 < end; e += 8) {
    uint2 r0 = recs[e];
    uint2 r1 = recs[e + 4];
    int o0 = r0.x & 0xFFFF, p0 = (r0.x >> 16) & 0x3F;
    int o1 = r1.x & 0xFFFF, p1 = (r1.x >> 16) & 0x3F;
    unsigned short h0 = *reinterpret_cast<const unsigned short*>(
        &H2[(size_t)o0 * NC + p0 * WSZ + c]);
    unsigned short h1v = *reinterpret_cast<const unsigned short*>(
        &H2[(size_t)o1 * NC + p1 * WSZ + c]);
    acc += __uint_as_float(r0.y) * bf2f(h0);
    acc += __uint_as_float(r1.y) * bf2f(h1v);
  }
  if (e < end) {
    uint2 r = recs[e];
    int o = r.x & 0xFFFF, p = (r.x >> 16) & 0x3F;
    unsigned short h = *reinterpret_cast<const unsigned short*>(
        &H2[(size_t)o * NC + p * WSZ + c]);
    acc += __uint_as_float(r.y) * bf2f(h);
  }
  acc += __shfl_xor(acc, 16, 64);
  acc += __shfl_xor(acc, 32, 64);
  if (lane < CC) out[wid * CC + c] = acc + bias2[c];
}

// ---------------- launcher ----------------
extern "C" void kernel_launch(void* const* d_in, const int* in_sizes, int n_in,
                              void* d_out, int out_size, void* d_ws, size_t ws_size,
                              hipStream_t stream) {
  const float* emb = (const float*)d_in[0];
  const float* w1  = (const float*)d_in[1];
  const float* b1  = (const float*)d_in[2];
  const float* w2  = (const float*)d_in[3];
  const float* b2  = (const float*)d_in[4];
  const float* ev  = (const float*)d_in[5];
  const int*   es  = (const int*)d_in[6];
  const int*   ep  = (const int*)d_in[7];
  const int*   eo  = (const int*)d_in[8];
  float* out = (float*)d_out;

  char* ws = (char*)d_ws;
  size_t off = 0;
  auto alloc = [&](size_t bytes) -> void* {
    void* p = ws + off;
    off = (off + bytes + 255) & ~(size_t)255;
    return p;
  };
  __hip_bfloat16* Bt  = (__hip_bfloat16*)alloc((size_t)NCP * DD * 2);  //   2 MB
  __hip_bfloat16* Hb  = (__hip_bfloat16*)alloc((size_t)NN * NC * 2);   // 52.8 MB
  __hip_bfloat16* H2  = (__hip_bfloat16*)alloc((size_t)NN * NC * 2);   // 52.8 MB
  float* h1   = (float*)alloc((size_t)NN * WSZ * 4);                   //  3.2 MB
  uint2* recs = (uint2*)alloc((size_t)EE * 8);                         // 25.6 MB
  int* counts = (int*)alloc((size_t)NN * 4);
  int* offs   = (int*)alloc((size_t)(NN + 1) * 4);
  int* ptr    = (int*)alloc((size_t)(NN + 1) * 4);
  int* bptr   = (int*)alloc((size_t)NBK * 4);
  int* part   = (int*)alloc((size_t)NBUSED * 4);
  int* bbase  = (int*)alloc((size_t)NBUSED * 4);
  // tmp aliases Hb (dead until k_gemm)
  uint2* tmp = (uint2*)Hb;

  hipMemsetAsync(counts, 0, (size_t)NN * 4, stream);

  k_bt_hist <<<16500, 256, 0, stream>>>(w1, Bt, es, counts);
  k_part    <<<NBUSED, 256, 0, stream>>>(counts, part);
  k_scan2   <<<1,      64, 0, stream>>>(part, bbase, bptr, offs);
  k_offs    <<<NBUSED,1024, 0, stream>>>(counts, bbase, offs, ptr);
  k_bucket  <<<(EE + MEDG - 1) / MEDG, 256, 0, stream>>>(es, ep, eo, ev, bptr, tmp);
  dim3 sg(NBUSED, SBPB);
  k_scatter2<<<sg,    256, 0, stream>>>(tmp, offs, ptr, recs);
  dim3 gg(5, 391);
  k_gemm    <<<gg,    256, 0, stream>>>(emb, Bt, Hb);
  k_agg1    <<<12500, 256, 0, stream>>>(recs, offs, Hb, b1, h1);
  k_h2      <<<103125,256, 0, stream>>>(h1, w2, H2);
  k_agg2    <<<12500, 256, 0, stream>>>(recs, offs, H2, b2, out);
}

// Round 6
// 1188.798 us; speedup vs baseline: 1.0746x; 1.0746x over previous
//
#include <hip/hip_runtime.h>
#include <hip/hip_bf16.h>
#include <stdint.h>

// Problem constants
#define NN 50000            // nodes
#define RR 33               // relations
#define EE 3200000          // edges
#define DD 1600             // emb dim
#define WSZ 16              // weights_size
#define CC 10               // classes
#define NC (RR*WSZ)         // 528 columns of H / H2
#define NCP 640             // padded to 5 * 128 column tiles

// Bucketed-scatter params
#define NBK 64              // bucket slots (49 used)
#define BSH 10              // bucket = s >> 10  (1024 nodes/bucket)
#define NBUSED ((NN + (1<<BSH) - 1) >> BSH)   // 49
#define MEDG 4096           // edges staged per block in pass A

typedef __attribute__((ext_vector_type(8))) short bfrag;   // 8 bf16 = 4 VGPRs
typedef __attribute__((ext_vector_type(4))) float f32x4;

__device__ __forceinline__ unsigned short f2bf(float f) {
  union { float f; unsigned u; } v; v.f = f;
  unsigned r = v.u + 0x7FFF + ((v.u >> 16) & 1);   // RNE, inputs are finite
  return (unsigned short)(r >> 16);
}
__device__ __forceinline__ float bf2f(unsigned short h) {
  union { unsigned u; float f; } v; v.u = ((unsigned)h) << 16;
  return v.f;
}
// pack two fp32 -> two bf16 (round-to-nearest via +0x8000 bias; ~1 ulp max)
__device__ __forceinline__ unsigned pack2bf(float a, float b) {
  unsigned ua = __float_as_uint(a) + 0x8000u;
  unsigned ub = __float_as_uint(b) + 0x8000u;
  return (ua >> 16) | (ub & 0xFFFF0000u);
}

// ---------------- 1) fused: build B^T bf16 + edge_s histogram -----------------
// blocks [0, 4000): Bt[n][k] = w1[n>>4][k][n&15]; blocks [4000, 16500): hist
__global__ __launch_bounds__(256) void k_bt_hist(const float* __restrict__ w1,
                                                 __hip_bfloat16* __restrict__ bt,
                                                 const int* __restrict__ es,
                                                 int* __restrict__ counts) {
  int b = blockIdx.x;
  if (b < 4000) {
    int idx = b * 256 + threadIdx.x;                   // NCP*DD = 1,024,000 exact
    int n = idx / DD, k = idx - n * DD;
    float v = 0.f;
    if (n < NC) {
      int r = n >> 4, o = n & 15;
      v = w1[((size_t)r * DD + k) * WSZ + o];
    }
    *reinterpret_cast<unsigned short*>(&bt[idx]) = f2bf(v);
  } else {
    int i = (b - 4000) * 256 + threadIdx.x;            // EE exact
    atomicAdd(&counts[es[i]], 1);
  }
}

// ---------------- 3b-i) per-1024-chunk partial sums (coalesced) ---------------
__global__ __launch_bounds__(256) void k_part(const int* __restrict__ counts,
                                              int* __restrict__ part) {
  int b = blockIdx.x, t = threadIdx.x;                 // NBUSED blocks
  int base = b << BSH;
  int s = 0;
  for (int j = t; j < (1 << BSH); j += 256) {
    int i = base + j; if (i < NN) s += counts[i];
  }
#pragma unroll
  for (int off = 32; off; off >>= 1) s += __shfl_down(s, off, 64);
  __shared__ int ws[4];
  if ((t & 63) == 0) ws[t >> 6] = s;
  __syncthreads();
  if (t == 0) part[b] = ws[0] + ws[1] + ws[2] + ws[3];
}

// ---------------- 3b-ii) scan 49 partials (one wave) --------------------------
__global__ __launch_bounds__(64) void k_scan2(const int* __restrict__ part,
                                              int* __restrict__ bbase,
                                              int* __restrict__ bptr,
                                              int* __restrict__ offs) {
  int t = threadIdx.x;
  int v = (t < NBUSED) ? part[t] : 0;
  int incl = v;
#pragma unroll
  for (int off = 1; off < 64; off <<= 1) {
    int x = __shfl_up(incl, off, 64);
    if (t >= off) incl += x;
  }
  int excl = incl - v;
  if (t < NBUSED) { bbase[t] = excl; bptr[t] = excl; }
  else if (t < NBK) bptr[t] = EE;
  if (t == 63) offs[NN] = EE;                          // all edges counted
}

// ---------------- 3b-iii) per-chunk exclusive scan -> offs/ptr ----------------
__global__ __launch_bounds__(1024) void k_offs(const int* __restrict__ counts,
                                               const int* __restrict__ bbase,
                                               int* __restrict__ offs,
                                               int* __restrict__ ptr) {
  __shared__ int sc[1024];
  int b = blockIdx.x, t = threadIdx.x;                 // NBUSED blocks x 1024
  int node = (b << BSH) + t;
  int v = (node < NN) ? counts[node] : 0;
  sc[t] = v;
  __syncthreads();
  for (int off = 1; off < 1024; off <<= 1) {
    int x = (t >= off) ? sc[t - off] : 0;
    __syncthreads();
    sc[t] += x;
    __syncthreads();
  }
  int excl = sc[t] - v + bbase[b];
  if (node < NN) { offs[node] = excl; ptr[node] = excl; }
}

// ---------------- 3c pass A) LDS-staged bucket binning ------------------------
// tmp records grouped by bucket (s>>10); r.x = o | p<<16 | (s&1023)<<22
__global__ __launch_bounds__(256) void k_bucket(const int* __restrict__ es,
                                                const int* __restrict__ ep,
                                                const int* __restrict__ eo,
                                                const float* __restrict__ ev,
                                                int* __restrict__ bptr,
                                                uint2* __restrict__ tmp) {
  __shared__ int lhist[NBK];
  __shared__ int lofs[NBK];
  __shared__ int lcur[NBK];
  __shared__ int lbase[NBK];
  __shared__ uint2 stage[MEDG];
  __shared__ unsigned char sbk[MEDG];
  int tid = threadIdx.x;
  int e0 = blockIdx.x * MEDG;
  int n = EE - e0; if (n > MEDG) n = MEDG;
  for (int i = tid; i < NBK; i += 256) lhist[i] = 0;
  __syncthreads();
  for (int i = tid; i < n; i += 256)
    atomicAdd(&lhist[es[e0 + i] >> BSH], 1);
  __syncthreads();
  if (tid == 0) {
    int run = 0;
    for (int b = 0; b < NBK; ++b) { lofs[b] = run; run += lhist[b]; }
  }
  __syncthreads();
  if (tid < NBK) {
    lcur[tid] = lofs[tid];
    lbase[tid] = lhist[tid] ? atomicAdd(&bptr[tid], lhist[tid]) : 0;
  }
  __syncthreads();
  for (int i = tid; i < n; i += 256) {
    int s = es[e0 + i];
    int b = s >> BSH;
    int pos = atomicAdd(&lcur[b], 1);
    uint2 r;
    r.x = (unsigned)eo[e0 + i] | ((unsigned)ep[e0 + i] << 16)
        | ((unsigned)(s & 1023) << 22);
    r.y = __float_as_uint(ev[e0 + i]);
    stage[pos] = r;
    sbk[pos] = (unsigned char)b;
  }
  __syncthreads();
  for (int i = tid; i < n; i += 256) {                 // grouped -> ~sequential writes
    int b = sbk[i];
    tmp[lbase[b] + (i - lofs[b])] = stage[i];
  }
}

// ---------------- 3c pass B) within-bucket CSR scatter (L2-resident) ----------
#define SBPB 8               // sub-blocks per bucket
__global__ __launch_bounds__(256) void k_scatter2(const uint2* __restrict__ tmp,
                                                  const int* __restrict__ offs,
                                                  int* __restrict__ ptr,
                                                  uint2* __restrict__ recs) {
  int b = blockIdx.x;                                  // NBUSED x SBPB grid
  int n0 = b << BSH, n1 = (b + 1) << BSH;
  if (n1 > NN) n1 = NN;
  int start = offs[n0], endv = offs[n1];
  int tid = blockIdx.y * 256 + (int)threadIdx.x;
  for (int i = start + tid; i < endv; i += SBPB * 256) {
    uint2 r = tmp[i];
    int s = n0 + (int)(r.x >> 22);
    int pos = atomicAdd(&ptr[s], 1);
    recs[pos] = r;                                     // random within ~512KB: L2 absorbs
  }
}

// ---------------- 4) GEMM: Hb = emb(fp32, fused convert) @ B, bf16 out --------
// XCD-swizzled grid + double-buffered LDS software pipeline.
#define BM 128
#define BN 128
#define BK 32
#define NMT 391              // m-tiles
#define NNT 5                // n-tiles
#define MPX 49               // m-strips per XCD (8*49 >= 391)

__global__ __launch_bounds__(256) void k_gemm(const float* __restrict__ A,
                                              const __hip_bfloat16* __restrict__ Bt,
                                              __hip_bfloat16* __restrict__ Hb) {
  __shared__ __align__(16) __hip_bfloat16 As[2][BM * BK];   // 8 KB each
  __shared__ __align__(16) __hip_bfloat16 Bs[2][BN * BK];   // 8 KB each
  int tid  = threadIdx.x;
  int wave = tid >> 6, lane = tid & 63;

  // XCD-aware swizzle: consecutive blocks round-robin XCDs (L%8). Give each
  // XCD a contiguous band of m-strips; within an XCD the 5 n-tiles of one
  // strip are adjacent in per-XCD order -> A strip served by ONE L2.
  int L = blockIdx.x;
  int xcd = L & 7;
  int r = L >> 3;                       // 0..244
  int lm = r / NNT, nt = r - lm * NNT;
  int mt = xcd * MPX + lm;
  if (mt >= NMT) return;                // 5 no-op blocks
  int m0 = mt * BM, n0 = nt * BN;

  int wm = (wave >> 1) * 64, wn = (wave & 1) * 64;       // 2x2 wave quadrants
  int ld = lane & 15, quad = lane >> 4;

  // active-column mask per ni (wave-uniform): skip padded cols >= NC
  bool nact[4];
#pragma unroll
  for (int ni = 0; ni < 4; ++ni) nact[ni] = (n0 + wn + ni * 16) < NC;

  // A-staging addresses: 2 chunks of (row = idx>>2, kc = (idx&3)*8)
  int rowA[2], kcA[2];
#pragma unroll
  for (int j = 0; j < 2; ++j) {
    int idx = j * 256 + tid;
    int row = idx >> 2;
    kcA[j] = (idx & 3) * 8;
    int grow = m0 + row; if (grow > NN - 1) grow = NN - 1;
    rowA[j] = grow;
  }
  // B-staging addresses
  int colB[2], kcB[2];
#pragma unroll
  for (int j = 0; j < 2; ++j) {
    int idx = j * 256 + tid;
    colB[j] = n0 + (idx >> 2);
    kcB[j] = (idx & 3) * 8;
  }

  float4 va[2][2];
  // prologue: tile 0
#pragma unroll
  for (int j = 0; j < 2; ++j) {
    const float4* gp = (const float4*)(A + (size_t)rowA[j] * DD + kcA[j]);
    va[j][0] = gp[0]; va[j][1] = gp[1];
  }
#pragma unroll
  for (int j = 0; j < 2; ++j) {
    const __hip_bfloat16* gp = Bt + (size_t)colB[j] * DD + kcB[j];
    __builtin_amdgcn_global_load_lds(
        (const __attribute__((address_space(1))) void*)gp,
        (__attribute__((address_space(3))) void*)(Bs[0] + (j * 256 + tid) * 8),
        16, 0, 0);
  }
#pragma unroll
  for (int j = 0; j < 2; ++j) {
    uint4 w;
    w.x = pack2bf(va[j][0].x, va[j][0].y); w.y = pack2bf(va[j][0].z, va[j][0].w);
    w.z = pack2bf(va[j][1].x, va[j][1].y); w.w = pack2bf(va[j][1].z, va[j][1].w);
    *reinterpret_cast<uint4*>(As[0] + ((size_t)j * 256 + tid) * 8) = w;
  }
  __syncthreads();                                     // drains B0 DMA + A0 writes

  f32x4 acc[4][4] = {};

  for (int k0 = 0, it = 0; k0 < DD; k0 += BK, ++it) {
    int buf = it & 1, nbuf = buf ^ 1;
    bool more = (k0 + BK) < DD;
    if (more) {
      // issue next tile's loads first: B async DMA + A vector loads.
      // They complete during this tile's MFMA block.
#pragma unroll
      for (int j = 0; j < 2; ++j) {
        const __hip_bfloat16* gp = Bt + (size_t)colB[j] * DD + k0 + BK + kcB[j];
        __builtin_amdgcn_global_load_lds(
            (const __attribute__((address_space(1))) void*)gp,
            (__attribute__((address_space(3))) void*)(Bs[nbuf] + (j * 256 + tid) * 8),
            16, 0, 0);
      }
#pragma unroll
      for (int j = 0; j < 2; ++j) {
        const float4* gp = (const float4*)(A + (size_t)rowA[j] * DD + k0 + BK + kcA[j]);
        va[j][0] = gp[0]; va[j][1] = gp[1];
      }
    }

    bfrag af[4], bf[4];
#pragma unroll
    for (int mi = 0; mi < 4; ++mi)
      af[mi] = *(const bfrag*)(As[buf] + (wm + mi * 16 + ld) * BK + quad * 8);
#pragma unroll
    for (int ni = 0; ni < 4; ++ni)
      if (nact[ni])
        bf[ni] = *(const bfrag*)(Bs[buf] + (wn + ni * 16 + ld) * BK + quad * 8);
#pragma unroll
    for (int mi = 0; mi < 4; ++mi)
#pragma unroll
      for (int ni = 0; ni < 4; ++ni)
        if (nact[ni])
          acc[mi][ni] = __builtin_amdgcn_mfma_f32_16x16x32_bf16(af[mi], bf[ni],
                                                                acc[mi][ni], 0, 0, 0);
    if (more) {
      // pack+write next A tile (loads have had the MFMA block to land)
#pragma unroll
      for (int j = 0; j < 2; ++j) {
        uint4 w;
        w.x = pack2bf(va[j][0].x, va[j][0].y); w.y = pack2bf(va[j][0].z, va[j][0].w);
        w.z = pack2bf(va[j][1].x, va[j][1].y); w.w = pack2bf(va[j][1].z, va[j][1].w);
        *reinterpret_cast<uint4*>(As[nbuf] + ((size_t)j * 256 + tid) * 8) = w;
      }
      __syncthreads();   // nbuf writes visible; own buf-reads already drained
    }
  }

#pragma unroll
  for (int mi = 0; mi < 4; ++mi)
#pragma unroll
    for (int ni = 0; ni < 4; ++ni) {
      int col = n0 + wn + ni * 16 + ld;
      if (col >= NC) continue;
#pragma unroll
      for (int r2 = 0; r2 < 4; ++r2) {
        int row = m0 + wm + mi * 16 + quad * 4 + r2;     // C/D: col=lane&15, row=quad*4+reg
        if (row < NN)
          *reinterpret_cast<unsigned short*>(&Hb[(size_t)row * NC + col]) =
              f2bf(acc[mi][ni][r2]);
      }
    }
}

// ---------------- 5) layer-1 aggregation: one wave per destination node -------
__global__ __launch_bounds__(256) void k_agg1(const uint2* __restrict__ recs,
                                              const int* __restrict__ offs,
                                              const __hip_bfloat16* __restrict__ Hb,
                                              const float* __restrict__ bias1,
                                              float* __restrict__ h1) {
  int wid  = (blockIdx.x * 256 + threadIdx.x) >> 6;      // exactly NN waves
  int lane = threadIdx.x & 63;
  int grp = lane >> 4, c = lane & 15;
  int beg = offs[wid], end = offs[wid + 1];
  float acc = 0.f;
  int e = beg + grp;
  for (; e + 4 < end; e += 8) {                          // 2x unroll: 2 chains in flight
    uint2 r0 = recs[e];
    uint2 r1 = recs[e + 4];
    int o0 = r0.x & 0xFFFF, p0 = (r0.x >> 16) & 0x3F;
    int o1 = r1.x & 0xFFFF, p1 = (r1.x >> 16) & 0x3F;
    unsigned short h0 = *reinterpret_cast<const unsigned short*>(
        &Hb[(size_t)o0 * NC + p0 * WSZ + c]);
    unsigned short h1v = *reinterpret_cast<const unsigned short*>(
        &Hb[(size_t)o1 * NC + p1 * WSZ + c]);
    acc += __uint_as_float(r0.y) * bf2f(h0);
    acc += __uint_as_float(r1.y) * bf2f(h1v);
  }
  if (e < end) {
    uint2 r = recs[e];
    int o = r.x & 0xFFFF, p = (r.x >> 16) & 0x3F;
    unsigned short h = *reinterpret_cast<const unsigned short*>(
        &Hb[(size_t)o * NC + p * WSZ + c]);
    acc += __uint_as_float(r.y) * bf2f(h);
  }
  acc += __shfl_xor(acc, 16, 64);
  acc += __shfl_xor(acc, 32, 64);
  if (lane < 16) h1[wid * WSZ + c] = fmaxf(acc + bias1[c], 0.f);
}

// ---------------- 6a) dense layer-2 projection: H2[n][p*16+c], bf16 out -------
__global__ __launch_bounds__(256) void k_h2(const float* __restrict__ h1,
                                            const float* __restrict__ w2,
                                            __hip_bfloat16* __restrict__ H2) {
  __shared__ float w2s[RR * WSZ * CC];                   // 21.1 KB
  for (int i = threadIdx.x; i < RR * WSZ * CC; i += 256) w2s[i] = w2[i];
  __syncthreads();
  int idx = blockIdx.x * 256 + threadIdx.x;              // NN*NC = 26,400,000 exact
  int n = idx / NC, j = idx - n * NC;
  int p = j >> 4, c = j & 15;
  float dot = 0.f;
  if (c < CC) {
    const float* hp = h1 + n * WSZ;
    const float* wp = w2s + p * WSZ * CC + c;
#pragma unroll
    for (int i2 = 0; i2 < WSZ; ++i2) dot += hp[i2] * wp[i2 * CC];
  }
  *reinterpret_cast<unsigned short*>(&H2[idx]) = f2bf(dot);
}

// ---------------- 6b) layer-2 aggregation: pure gather ------------------------
__global__ __launch_bounds__(256) void k_agg2(const uint2* __restrict__ recs,
                                              const int* __restrict__ offs,
                                              const __hip_bfloat16* __restrict__ H2,
                                              const float* __restrict__ bias2,
                                              float* __restrict__ out) {
  int wid  = (blockIdx.x * 256 + threadIdx.x) >> 6;      // exactly NN waves
  int lane = threadIdx.x & 63;
  int grp = lane >> 4, c = lane & 15;
  int beg = offs[wid], end = offs[wid + 1];
  float acc = 0.f;
  int e = beg + grp;
  for (; e + 4 < end; e += 8) {
    uint2 r0 = recs[e];
    uint2 r1 = recs[e + 4];
    int o0 = r0.x & 0xFFFF, p0 = (r0.x >> 16) & 0x3F;
    int o1 = r1.x & 0xFFFF, p1 = (r1.x >> 16) & 0x3F;
    unsigned short h0 = *reinterpret_cast<const unsigned short*>(
        &H2[(size_t)o0 * NC + p0 * WSZ + c]);
    unsigned short h1v = *reinterpret_cast<const unsigned short*>(
        &H2[(size_t)o1 * NC + p1 * WSZ + c]);
    acc += __uint_as_float(r0.y) * bf2f(h0);
    acc += __uint_as_float(r1.y) * bf2f(h1v);
  }
  if (e < end) {
    uint2 r = recs[e];
    int o = r.x & 0xFFFF, p = (r.x >> 16) & 0x3F;
    unsigned short h = *reinterpret_cast<const unsigned short*>(
        &H2[(size_t)o * NC + p * WSZ + c]);
    acc += __uint_as_float(r.y) * bf2f(h);
  }
  acc += __shfl_xor(acc, 16, 64);
  acc += __shfl_xor(acc, 32, 64);
  if (lane < CC) out[wid * CC + c] = acc + bias2[c];
}

// ---------------- launcher ----------------
extern "C" void kernel_launch(void* const* d_in, const int* in_sizes, int n_in,
                              void* d_out, int out_size, void* d_ws, size_t ws_size,
                              hipStream_t stream) {
  const float* emb = (const float*)d_in[0];
  const float* w1  = (const float*)d_in[1];
  const float* b1  = (const float*)d_in[2];
  const float* w2  = (const float*)d_in[3];
  const float* b2  = (const float*)d_in[4];
  const float* ev  = (const float*)d_in[5];
  const int*   es  = (const int*)d_in[6];
  const int*   ep  = (const int*)d_in[7];
  const int*   eo  = (const int*)d_in[8];
  float* out = (float*)d_out;

  char* ws = (char*)d_ws;
  size_t off = 0;
  auto alloc = [&](size_t bytes) -> void* {
    void* p = ws + off;
    off = (off + bytes + 255) & ~(size_t)255;
    return p;
  };
  __hip_bfloat16* Bt  = (__hip_bfloat16*)alloc((size_t)NCP * DD * 2);  //   2 MB
  __hip_bfloat16* Hb  = (__hip_bfloat16*)alloc((size_t)NN * NC * 2);   // 52.8 MB
  __hip_bfloat16* H2  = (__hip_bfloat16*)alloc((size_t)NN * NC * 2);   // 52.8 MB
  float* h1   = (float*)alloc((size_t)NN * WSZ * 4);                   //  3.2 MB
  uint2* recs = (uint2*)alloc((size_t)EE * 8);                         // 25.6 MB
  int* counts = (int*)alloc((size_t)NN * 4);
  int* offs   = (int*)alloc((size_t)(NN + 1) * 4);
  int* ptr    = (int*)alloc((size_t)(NN + 1) * 4);
  int* bptr   = (int*)alloc((size_t)NBK * 4);
  int* part   = (int*)alloc((size_t)NBUSED * 4);
  int* bbase  = (int*)alloc((size_t)NBUSED * 4);
  // tmp aliases Hb (dead until k_gemm)
  uint2* tmp = (uint2*)Hb;

  hipMemsetAsync(counts, 0, (size_t)NN * 4, stream);

  k_bt_hist <<<16500, 256, 0, stream>>>(w1, Bt, es, counts);
  k_part    <<<NBUSED, 256, 0, stream>>>(counts, part);
  k_scan2   <<<1,      64, 0, stream>>>(part, bbase, bptr, offs);
  k_offs    <<<NBUSED,1024, 0, stream>>>(counts, bbase, offs, ptr);
  k_bucket  <<<(EE + MEDG - 1) / MEDG, 256, 0, stream>>>(es, ep, eo, ev, bptr, tmp);
  dim3 sg(NBUSED, SBPB);
  k_scatter2<<<sg,    256, 0, stream>>>(tmp, offs, ptr, recs);
  k_gemm    <<<8 * MPX * NNT, 256, 0, stream>>>(emb, Bt, Hb);   // 1960 blocks
  k_agg1    <<<12500, 256, 0, stream>>>(recs, offs, Hb, b1, h1);
  k_h2      <<<103125,256, 0, stream>>>(h1, w2, H2);
  k_agg2    <<<12500, 256, 0, stream>>>(recs, offs, H2, b2, out);
}

// Round 7
// 1188.229 us; speedup vs baseline: 1.0751x; 1.0005x over previous
//
#include <hip/hip_runtime.h>
#include <hip/hip_bf16.h>
#include <stdint.h>

// Problem constants
#define NN 50000            // nodes
#define RR 33               // relations
#define EE 3200000          // edges
#define DD 1600             // emb dim
#define WSZ 16              // weights_size
#define CC 10               // classes
#define NC (RR*WSZ)         // 528 columns of H / H2
#define NCP 640             // padded to 5 * 128 column tiles

// Bucketed-scatter params
#define NBK 64              // bucket slots (49 used)
#define BSH 10              // bucket = s >> 10  (1024 nodes/bucket)
#define NBUSED ((NN + (1<<BSH) - 1) >> BSH)   // 49
#define MEDG 4096           // edges staged per block in pass A

typedef __attribute__((ext_vector_type(8))) short bfrag;   // 8 bf16 = 4 VGPRs
typedef __attribute__((ext_vector_type(4))) float f32x4;

__device__ __forceinline__ unsigned short f2bf(float f) {
  union { float f; unsigned u; } v; v.f = f;
  unsigned r = v.u + 0x7FFF + ((v.u >> 16) & 1);   // RNE, inputs are finite
  return (unsigned short)(r >> 16);
}
__device__ __forceinline__ float bf2f(unsigned short h) {
  union { unsigned u; float f; } v; v.u = ((unsigned)h) << 16;
  return v.f;
}
// pack two fp32 -> two bf16 (round-to-nearest via +0x8000 bias; ~1 ulp max)
__device__ __forceinline__ unsigned pack2bf(float a, float b) {
  unsigned ua = __float_as_uint(a) + 0x8000u;
  unsigned ub = __float_as_uint(b) + 0x8000u;
  return (ua >> 16) | (ub & 0xFFFF0000u);
}

// ---------------- 1) fused: build B^T bf16 + edge_s histogram -----------------
__global__ __launch_bounds__(256) void k_bt_hist(const float* __restrict__ w1,
                                                 __hip_bfloat16* __restrict__ bt,
                                                 const int* __restrict__ es,
                                                 int* __restrict__ counts) {
  int b = blockIdx.x;
  if (b < 4000) {
    int idx = b * 256 + threadIdx.x;                   // NCP*DD = 1,024,000 exact
    int n = idx / DD, k = idx - n * DD;
    float v = 0.f;
    if (n < NC) {
      int r = n >> 4, o = n & 15;
      v = w1[((size_t)r * DD + k) * WSZ + o];
    }
    *reinterpret_cast<unsigned short*>(&bt[idx]) = f2bf(v);
  } else {
    int i = (b - 4000) * 256 + threadIdx.x;            // EE exact
    atomicAdd(&counts[es[i]], 1);
  }
}

// ---------------- 3b-i) per-1024-chunk partial sums (coalesced) ---------------
__global__ __launch_bounds__(256) void k_part(const int* __restrict__ counts,
                                              int* __restrict__ part) {
  int b = blockIdx.x, t = threadIdx.x;                 // NBUSED blocks
  int base = b << BSH;
  int s = 0;
  for (int j = t; j < (1 << BSH); j += 256) {
    int i = base + j; if (i < NN) s += counts[i];
  }
#pragma unroll
  for (int off = 32; off; off >>= 1) s += __shfl_down(s, off, 64);
  __shared__ int ws[4];
  if ((t & 63) == 0) ws[t >> 6] = s;
  __syncthreads();
  if (t == 0) part[b] = ws[0] + ws[1] + ws[2] + ws[3];
}

// ---------------- 3b-ii) scan 49 partials (one wave) --------------------------
__global__ __launch_bounds__(64) void k_scan2(const int* __restrict__ part,
                                              int* __restrict__ bbase,
                                              int* __restrict__ bptr,
                                              int* __restrict__ offs) {
  int t = threadIdx.x;
  int v = (t < NBUSED) ? part[t] : 0;
  int incl = v;
#pragma unroll
  for (int off = 1; off < 64; off <<= 1) {
    int x = __shfl_up(incl, off, 64);
    if (t >= off) incl += x;
  }
  int excl = incl - v;
  if (t < NBUSED) { bbase[t] = excl; bptr[t] = excl; }
  else if (t < NBK) bptr[t] = EE;
  if (t == 63) offs[NN] = EE;                          // all edges counted
}

// ---------------- 3b-iii) per-chunk exclusive scan -> offs/ptr ----------------
__global__ __launch_bounds__(1024) void k_offs(const int* __restrict__ counts,
                                               const int* __restrict__ bbase,
                                               int* __restrict__ offs,
                                               int* __restrict__ ptr) {
  __shared__ int sc[1024];
  int b = blockIdx.x, t = threadIdx.x;                 // NBUSED blocks x 1024
  int node = (b << BSH) + t;
  int v = (node < NN) ? counts[node] : 0;
  sc[t] = v;
  __syncthreads();
  for (int off = 1; off < 1024; off <<= 1) {
    int x = (t >= off) ? sc[t - off] : 0;
    __syncthreads();
    sc[t] += x;
    __syncthreads();
  }
  int excl = sc[t] - v + bbase[b];
  if (node < NN) { offs[node] = excl; ptr[node] = excl; }
}

// ---------------- 3c pass A) LDS-staged bucket binning ------------------------
__global__ __launch_bounds__(256) void k_bucket(const int* __restrict__ es,
                                                const int* __restrict__ ep,
                                                const int* __restrict__ eo,
                                                const float* __restrict__ ev,
                                                int* __restrict__ bptr,
                                                uint2* __restrict__ tmp) {
  __shared__ int lhist[NBK];
  __shared__ int lofs[NBK];
  __shared__ int lcur[NBK];
  __shared__ int lbase[NBK];
  __shared__ uint2 stage[MEDG];
  __shared__ unsigned char sbk[MEDG];
  int tid = threadIdx.x;
  int e0 = blockIdx.x * MEDG;
  int n = EE - e0; if (n > MEDG) n = MEDG;
  for (int i = tid; i < NBK; i += 256) lhist[i] = 0;
  __syncthreads();
  for (int i = tid; i < n; i += 256)
    atomicAdd(&lhist[es[e0 + i] >> BSH], 1);
  __syncthreads();
  if (tid == 0) {
    int run = 0;
    for (int b = 0; b < NBK; ++b) { lofs[b] = run; run += lhist[b]; }
  }
  __syncthreads();
  if (tid < NBK) {
    lcur[tid] = lofs[tid];
    lbase[tid] = lhist[tid] ? atomicAdd(&bptr[tid], lhist[tid]) : 0;
  }
  __syncthreads();
  for (int i = tid; i < n; i += 256) {
    int s = es[e0 + i];
    int b = s >> BSH;
    int pos = atomicAdd(&lcur[b], 1);
    uint2 r;
    r.x = (unsigned)eo[e0 + i] | ((unsigned)ep[e0 + i] << 16)
        | ((unsigned)(s & 1023) << 22);
    r.y = __float_as_uint(ev[e0 + i]);
    stage[pos] = r;
    sbk[pos] = (unsigned char)b;
  }
  __syncthreads();
  for (int i = tid; i < n; i += 256) {                 // grouped -> ~sequential writes
    int b = sbk[i];
    tmp[lbase[b] + (i - lofs[b])] = stage[i];
  }
}

// ---------------- 3c pass B) within-bucket CSR scatter (L2-resident) ----------
#define SBPB 8               // sub-blocks per bucket
__global__ __launch_bounds__(256) void k_scatter2(const uint2* __restrict__ tmp,
                                                  const int* __restrict__ offs,
                                                  int* __restrict__ ptr,
                                                  uint2* __restrict__ recs) {
  int b = blockIdx.x;                                  // NBUSED x SBPB grid
  int n0 = b << BSH, n1 = (b + 1) << BSH;
  if (n1 > NN) n1 = NN;
  int start = offs[n0], endv = offs[n1];
  int tid = blockIdx.y * 256 + (int)threadIdx.x;
  for (int i = start + tid; i < endv; i += SBPB * 256) {
    uint2 r = tmp[i];
    int s = n0 + (int)(r.x >> 22);
    int pos = atomicAdd(&ptr[s], 1);
    recs[pos] = r;                                     // random within ~512KB: L2 absorbs
  }
}

// ---------------- 4) GEMM: Hb = emb(fp32, fused convert) @ B, bf16 out --------
// XCD swizzle + bank-swizzled LDS + 2-deep A prefetch crossing raw s_barrier.
#define BM 128
#define BN 128
#define BK 32
#define NMT 391              // m-tiles
#define NNT 5                // n-tiles
#define MPX 49               // m-strips per XCD (8*49 >= 391)
#define KIT (DD / BK)        // 50 K-iterations

// fine barrier: drain LDS + the 2 oldest vm ops (the B DMAs); leave the 8
// newer A prefetch loads in flight across the barrier.
#define BAR_FINE() asm volatile("s_waitcnt vmcnt(8) lgkmcnt(0)\n\ts_barrier" ::: "memory")

__global__ __launch_bounds__(256) void k_gemm(const float* __restrict__ A,
                                              const __hip_bfloat16* __restrict__ Bt,
                                              __hip_bfloat16* __restrict__ Hb) {
  __shared__ __align__(16) __hip_bfloat16 As[2][BM * BK];   // 8 KB each
  __shared__ __align__(16) __hip_bfloat16 Bs[2][BN * BK];   // 8 KB each
  int tid  = threadIdx.x;
  int wave = tid >> 6, lane = tid & 63;

  // XCD-aware swizzle: L%8 = XCD; per XCD a contiguous band of m-strips,
  // 5 n-tiles of a strip adjacent -> A strip served by ONE L2.
  int L = blockIdx.x;
  int xcd = L & 7;
  int r = L >> 3;
  int lm = r / NNT, nt = r - lm * NNT;
  int mt = xcd * MPX + lm;
  if (mt >= NMT) return;                // 5 no-op blocks (before any barrier)
  int m0 = mt * BM, n0 = nt * BN;

  int wm = (wave >> 1) * 64, wn = (wave & 1) * 64;       // 2x2 wave quadrants
  int ld = lane & 15, quad = lane >> 4;

  bool nact[4];
#pragma unroll
  for (int ni = 0; ni < 4; ++ni) nact[ni] = (n0 + wn + ni * 16) < NC;

  // ---- staging thread roles ----
  size_t rowAg[2];  int kcA[2];  int wofsA[2];           // A: load + swizzled LDS write
  size_t srcB[2];                                        // B: swizzled DMA source
#pragma unroll
  for (int j = 0; j < 2; ++j) {
    int idx = j * 256 + tid;
    int lrow = idx >> 2, kq = idx & 3;
    kcA[j] = kq * 8;
    int grow = m0 + lrow; if (grow > NN - 1) grow = NN - 1;
    rowAg[j] = (size_t)grow * DD;
    wofsA[j] = lrow * BK + ((kq + ((lrow >> 1) & 3)) & 3) * 8;   // XOR chunk swizzle
    int lcol = idx >> 2, pc = idx & 3;
    int kqsrc = (pc - ((lcol >> 1) & 3)) & 3;            // inverse swizzle on source
    srcB[j] = (size_t)(n0 + lcol) * DD + kqsrc * 8;
  }
  // fragment read offsets (swizzle term is mi/ni-invariant: (x+16)>>1 = x>>1+8)
  int swA = ((wm + ld) >> 1) & 3;
  int swB = ((wn + ld) >> 1) & 3;
  int rchA = ((quad + swA) & 3) * 8;
  int rchB = ((quad + swB) & 3) * 8;

  auto dmaB = [&](int k0, __hip_bfloat16* dst) {
#pragma unroll
    for (int j = 0; j < 2; ++j) {
      const __hip_bfloat16* gp = Bt + srcB[j] + k0;
      __builtin_amdgcn_global_load_lds(
          (const __attribute__((address_space(1))) void*)gp,
          (__attribute__((address_space(3))) void*)(dst + ((size_t)j * 256 + tid) * 8),
          16, 0, 0);
    }
  };
  float4 va[2][2][2];
  auto loadA = [&](int k0, int slot) {
#pragma unroll
    for (int j = 0; j < 2; ++j) {
      const float4* gp = (const float4*)(A + rowAg[j] + k0 + kcA[j]);
      va[slot][j][0] = gp[0]; va[slot][j][1] = gp[1];
    }
  };
  auto packA = [&](int slot, __hip_bfloat16* dst) {
#pragma unroll
    for (int j = 0; j < 2; ++j) {
      uint4 w;
      w.x = pack2bf(va[slot][j][0].x, va[slot][j][0].y);
      w.y = pack2bf(va[slot][j][0].z, va[slot][j][0].w);
      w.z = pack2bf(va[slot][j][1].x, va[slot][j][1].y);
      w.w = pack2bf(va[slot][j][1].z, va[slot][j][1].w);
      *reinterpret_cast<uint4*>(dst + wofsA[j]) = w;
    }
  };

  f32x4 acc[4][4] = {};
  auto mfmaTile = [&](const __hip_bfloat16* as, const __hip_bfloat16* bs) {
    bfrag af[4], bf[4];
#pragma unroll
    for (int mi = 0; mi < 4; ++mi)
      af[mi] = *(const bfrag*)(as + (wm + mi * 16 + ld) * BK + rchA);
#pragma unroll
    for (int ni = 0; ni < 4; ++ni)
      if (nact[ni])
        bf[ni] = *(const bfrag*)(bs + (wn + ni * 16 + ld) * BK + rchB);
#pragma unroll
    for (int mi = 0; mi < 4; ++mi)
#pragma unroll
      for (int ni = 0; ni < 4; ++ni)
        if (nact[ni])
          acc[mi][ni] = __builtin_amdgcn_mfma_f32_16x16x32_bf16(af[mi], bf[ni],
                                                                acc[mi][ni], 0, 0, 0);
  };

  // ---- prologue: T0 staged, T1 loads in regs ----
  loadA(0, 0);
  dmaB(0, Bs[0]);
  packA(0, As[0]);
  loadA(BK, 1);
  __syncthreads();

  // ---- main loop: it = 0..KIT-3 (48 iters), full 2-deep pipeline ----
#pragma unroll 2
  for (int it = 0; it < KIT - 2; ++it) {
    int buf = it & 1, nbuf = buf ^ 1;
    int k0 = it * BK;
    dmaB(k0 + BK, Bs[nbuf]);                 // oldest vm ops this iter
    __builtin_amdgcn_sched_barrier(0);       // keep DMA before A loads in vmcnt order
    loadA(k0 + 2 * BK, buf);                 // 8 loads that CROSS the barrier
    mfmaTile(As[buf], Bs[buf]);
    packA(nbuf, As[nbuf]);                   // consumes loads issued LAST iter
    BAR_FINE();                              // vmcnt(8): B done, A prefetch in flight
  }
  // ---- it = KIT-2 (48): no A issue; full drain barrier ----
  {
    int buf = (KIT - 2) & 1, nbuf = buf ^ 1;
    dmaB((KIT - 1) * BK, Bs[nbuf]);
    mfmaTile(As[buf], Bs[buf]);
    packA(nbuf, As[nbuf]);
    __syncthreads();
  }
  // ---- it = KIT-1 (49): compute only ----
  mfmaTile(As[(KIT - 1) & 1], Bs[(KIT - 1) & 1]);

  // ---- epilogue ----
#pragma unroll
  for (int mi = 0; mi < 4; ++mi)
#pragma unroll
    for (int ni = 0; ni < 4; ++ni) {
      int col = n0 + wn + ni * 16 + ld;
      if (col >= NC) continue;
#pragma unroll
      for (int r2 = 0; r2 < 4; ++r2) {
        int row = m0 + wm + mi * 16 + quad * 4 + r2;     // C/D: col=lane&15, row=quad*4+reg
        if (row < NN)
          *reinterpret_cast<unsigned short*>(&Hb[(size_t)row * NC + col]) =
              f2bf(acc[mi][ni][r2]);
      }
    }
}

// ---------------- 5) layer-1 aggregation: one wave per destination node -------
__global__ __launch_bounds__(256) void k_agg1(const uint2* __restrict__ recs,
                                              const int* __restrict__ offs,
                                              const __hip_bfloat16* __restrict__ Hb,
                                              const float* __restrict__ bias1,
                                              float* __restrict__ h1) {
  int wid  = (blockIdx.x * 256 + threadIdx.x) >> 6;      // exactly NN waves
  int lane = threadIdx.x & 63;
  int grp = lane >> 4, c = lane & 15;
  int beg = offs[wid], end = offs[wid + 1];
  float acc = 0.f;
  int e = beg + grp;
  for (; e + 4 < end; e += 8) {                          // 2x unroll: 2 chains in flight
    uint2 r0 = recs[e];
    uint2 r1 = recs[e + 4];
    int o0 = r0.x & 0xFFFF, p0 = (r0.x >> 16) & 0x3F;
    int o1 = r1.x & 0xFFFF, p1 = (r1.x >> 16) & 0x3F;
    unsigned short h0 = *reinterpret_cast<const unsigned short*>(
        &Hb[(size_t)o0 * NC + p0 * WSZ + c]);
    unsigned short h1v = *reinterpret_cast<const unsigned short*>(
        &Hb[(size_t)o1 * NC + p1 * WSZ + c]);
    acc += __uint_as_float(r0.y) * bf2f(h0);
    acc += __uint_as_float(r1.y) * bf2f(h1v);
  }
  if (e < end) {
    uint2 r = recs[e];
    int o = r.x & 0xFFFF, p = (r.x >> 16) & 0x3F;
    unsigned short h = *reinterpret_cast<const unsigned short*>(
        &Hb[(size_t)o * NC + p * WSZ + c]);
    acc += __uint_as_float(r.y) * bf2f(h);
  }
  acc += __shfl_xor(acc, 16, 64);
  acc += __shfl_xor(acc, 32, 64);
  if (lane < 16) h1[wid * WSZ + c] = fmaxf(acc + bias1[c], 0.f);
}

// ---------------- 6a) dense layer-2 projection: H2[n][p*16+c], bf16 out -------
__global__ __launch_bounds__(256) void k_h2(const float* __restrict__ h1,
                                            const float* __restrict__ w2,
                                            __hip_bfloat16* __restrict__ H2) {
  __shared__ float w2s[RR * WSZ * CC];                   // 21.1 KB
  for (int i = threadIdx.x; i < RR * WSZ * CC; i += 256) w2s[i] = w2[i];
  __syncthreads();
  int idx = blockIdx.x * 256 + threadIdx.x;              // NN*NC = 26,400,000 exact
  int n = idx / NC, j = idx - n * NC;
  int p = j >> 4, c = j & 15;
  float dot = 0.f;
  if (c < CC) {
    const float* hp = h1 + n * WSZ;
    const float* wp = w2s + p * WSZ * CC + c;
#pragma unroll
    for (int i2 = 0; i2 < WSZ; ++i2) dot += hp[i2] * wp[i2 * CC];
  }
  *reinterpret_cast<unsigned short*>(&H2[idx]) = f2bf(dot);
}

// ---------------- 6b) layer-2 aggregation: pure gather ------------------------
__global__ __launch_bounds__(256) void k_agg2(const uint2* __restrict__ recs,
                                              const int* __restrict__ offs,
                                              const __hip_bfloat16* __restrict__ H2,
                                              const float* __restrict__ bias2,
                                              float* __restrict__ out) {
  int wid  = (blockIdx.x * 256 + threadIdx.x) >> 6;      // exactly NN waves
  int lane = threadIdx.x & 63;
  int grp = lane >> 4, c = lane & 15;
  int beg = offs[wid], end = offs[wid + 1];
  float acc = 0.f;
  int e = beg + grp;
  for (; e + 4 < end; e += 8) {
    uint2 r0 = recs[e];
    uint2 r1 = recs[e + 4];
    int o0 = r0.x & 0xFFFF, p0 = (r0.x >> 16) & 0x3F;
    int o1 = r1.x & 0xFFFF, p1 = (r1.x >> 16) & 0x3F;
    unsigned short h0 = *reinterpret_cast<const unsigned short*>(
        &H2[(size_t)o0 * NC + p0 * WSZ + c]);
    unsigned short h1v = *reinterpret_cast<const unsigned short*>(
        &H2[(size_t)o1 * NC + p1 * WSZ + c]);
    acc += __uint_as_float(r0.y) * bf2f(h0);
    acc += __uint_as_float(r1.y) * bf2f(h1v);
  }
  if (e < end) {
    uint2 r = recs[e];
    int o = r.x & 0xFFFF, p = (r.x >> 16) & 0x3F;
    unsigned short h = *reinterpret_cast<const unsigned short*>(
        &H2[(size_t)o * NC + p * WSZ + c]);
    acc += __uint_as_float(r.y) * bf2f(h);
  }
  acc += __shfl_xor(acc, 16, 64);
  acc += __shfl_xor(acc, 32, 64);
  if (lane < CC) out[wid * CC + c] = acc + bias2[c];
}

// ---------------- launcher ----------------
extern "C" void kernel_launch(void* const* d_in, const int* in_sizes, int n_in,
                              void* d_out, int out_size, void* d_ws, size_t ws_size,
                              hipStream_t stream) {
  const float* emb = (const float*)d_in[0];
  const float* w1  = (const float*)d_in[1];
  const float* b1  = (const float*)d_in[2];
  const float* w2  = (const float*)d_in[3];
  const float* b2  = (const float*)d_in[4];
  const float* ev  = (const float*)d_in[5];
  const int*   es  = (const int*)d_in[6];
  const int*   ep  = (const int*)d_in[7];
  const int*   eo  = (const int*)d_in[8];
  float* out = (float*)d_out;

  char* ws = (char*)d_ws;
  size_t off = 0;
  auto alloc = [&](size_t bytes) -> void* {
    void* p = ws + off;
    off = (off + bytes + 255) & ~(size_t)255;
    return p;
  };
  __hip_bfloat16* Bt  = (__hip_bfloat16*)alloc((size_t)NCP * DD * 2);  //   2 MB
  __hip_bfloat16* Hb  = (__hip_bfloat16*)alloc((size_t)NN * NC * 2);   // 52.8 MB
  __hip_bfloat16* H2  = (__hip_bfloat16*)alloc((size_t)NN * NC * 2);   // 52.8 MB
  float* h1   = (float*)alloc((size_t)NN * WSZ * 4);                   //  3.2 MB
  uint2* recs = (uint2*)alloc((size_t)EE * 8);                         // 25.6 MB
  int* counts = (int*)alloc((size_t)NN * 4);
  int* offs   = (int*)alloc((size_t)(NN + 1) * 4);
  int* ptr    = (int*)alloc((size_t)(NN + 1) * 4);
  int* bptr   = (int*)alloc((size_t)NBK * 4);
  int* part   = (int*)alloc((size_t)NBUSED * 4);
  int* bbase  = (int*)alloc((size_t)NBUSED * 4);
  // tmp aliases Hb (dead until k_gemm)
  uint2* tmp = (uint2*)Hb;

  hipMemsetAsync(counts, 0, (size_t)NN * 4, stream);

  k_bt_hist <<<16500, 256, 0, stream>>>(w1, Bt, es, counts);
  k_part    <<<NBUSED, 256, 0, stream>>>(counts, part);
  k_scan2   <<<1,      64, 0, stream>>>(part, bbase, bptr, offs);
  k_offs    <<<NBUSED,1024, 0, stream>>>(counts, bbase, offs, ptr);
  k_bucket  <<<(EE + MEDG - 1) / MEDG, 256, 0, stream>>>(es, ep, eo, ev, bptr, tmp);
  dim3 sg(NBUSED, SBPB);
  k_scatter2<<<sg,    256, 0, stream>>>(tmp, offs, ptr, recs);
  k_gemm    <<<8 * MPX * NNT, 256, 0, stream>>>(emb, Bt, Hb);   // 1960 blocks
  k_agg1    <<<12500, 256, 0, stream>>>(recs, offs, Hb, b1, h1);
  k_h2      <<<103125,256, 0, stream>>>(h1, w2, H2);
  k_agg2    <<<12500, 256, 0, stream>>>(recs, offs, H2, b2, out);
}